// Round 4
// baseline (372.650 us; speedup 1.0000x reference)
//
#include <hip/hip_runtime.h>

#define NC 32
#define NVOX (96*96*96)
#define NV2  (NVOX/2)     // 442368 float2-voxel pairs per sample
#define NB 384            // blocks per sample
#define TPB 256

// per-block workspace slot layout (floats)
#define WS_CE     0
#define WS_SP     32
#define WS_SPT    64
#define WS_SINKI  96
#define WS_SIB    100
#define WS_TGT    104
#define WS_HIST   128
#define SLOT_STRIDE 1152          // 128 + 1024
#define NSLOT     (2 * NB)        // 768
#define FINAL_OFF (NSLOT * SLOT_STRIDE)

__device__ __forceinline__ float wave_reduce(float v) {
    #pragma unroll
    for (int off = 32; off > 0; off >>= 1)
        v += __shfl_down(v, off, 64);
    return v;
}

__global__ __launch_bounds__(TPB, 3) void voxel_kernel(
    const float* __restrict__ images,
    const int*   __restrict__ targets,
    const int*   __restrict__ masks,     // bools promoted to 4-byte on device
    float* __restrict__ ws,
    float* __restrict__ pred_out)
{
    const int slot = blockIdx.x;
    const int b    = slot & 1;          // interleave samples across XCDs
    const int blk  = slot >> 1;
    const int tid  = threadIdx.x;

    __shared__ float s_hist[NC * NC];
    __shared__ float s_spt[NC];
    __shared__ float s_mf[NC];
    __shared__ float s_red[45];         // ce, sp[32], sinkI[4], sib[4], tgt[4]

    for (int i = tid; i < NC * NC; i += TPB) s_hist[i] = 0.f;
    if (tid < 45) s_red[tid] = 0.f;
    if (tid < NC) {
        s_spt[tid] = 0.f;
        s_mf[tid]  = (masks[b * NC + tid] != 0) ? 1.f : 0.f;
    }
    __syncthreads();

    const float2* img2 = (const float2*)(images + (size_t)b * NC * NVOX);
    const int2*   tgt2 = (const int2*)(targets + (size_t)b * NVOX);
    float2*       pout2 = (float2*)(pred_out + (size_t)b * NVOX);
    float*        wsb  = ws + (size_t)slot * SLOT_STRIDE;

    float sp[NC];
    #pragma unroll
    for (int c = 0; c < NC; ++c) sp[c] = 0.f;
    float ce = 0.f;
    float sinkI[4] = {0.f, 0.f, 0.f, 0.f};
    float sibc[4]  = {0.f, 0.f, 0.f, 0.f};
    float tgtc[4]  = {0.f, 0.f, 0.f, 0.f};

    for (int v2 = blk * TPB + tid; v2 < NV2; v2 += NB * TPB) {
        const int2 yy = tgt2[v2];
        const bool valid0 = (yy.x != 255);
        const bool valid1 = (yy.y != 255);
        const int  ys0 = valid0 ? yy.x : 0;
        const int  ys1 = valid1 ? yy.y : 0;
        const float vw0 = valid0 ? 1.f : 0.f;
        const float vw1 = valid1 ? 1.f : 0.f;

        // load 32 channels x 2 voxels; argmax over RAW x (first-max, strict >)
        float2 e[NC];
        float sum0 = 0.f, sum1 = 0.f;
        float best0 = -3.4e38f, best1 = -3.4e38f;
        int   pred0 = 4, pred1 = 4;
        #pragma unroll
        for (int c = 0; c < NC; ++c) {
            const float2 x = img2[(size_t)c * NV2 + v2];
            const float e0 = __expf(x.x);
            const float e1 = __expf(x.y);
            e[c] = make_float2(e0, e1);
            sum0 += e0;
            sum1 += e1;
            if (c >= 4) {
                if (x.x > best0) { best0 = x.x; pred0 = c; }
                if (x.y > best1) { best1 = x.y; pred1 = c; }
            }
        }
        const float rinv0 = 1.f / sum0;
        const float rinv1 = 1.f / sum1;
        pout2[v2] = make_float2((float)pred0, (float)pred1);

        const int pp0 = (pred0 - 4) / 7;
        const int pp1 = (pred1 - 4) / 7;
        const int py0 = (ys0 >= 4) ? (ys0 - 4) / 7 : -1;
        const int py1 = (ys1 >= 4) ? (ys1 - 4) / 7 : -1;

        // per-class prob sums + select p[y], p[parent(y)] for both halves
        float pyv0 = 0.f, ppv0 = 0.f, pyv1 = 0.f, ppv1 = 0.f;
        #pragma unroll
        for (int c = 0; c < NC; ++c) {
            const float p0 = e[c].x * rinv0;
            const float p1 = e[c].y * rinv1;
            sp[c] += p0 * vw0 + p1 * vw1;
            if (c == ys0) pyv0 = p0;
            if (c == py0) ppv0 = p0;
            if (c == ys1) pyv1 = p1;
            if (c == py1) ppv1 = p1;
        }

        // CE
        {
            float t0 = __logf(fminf(fmaxf(pyv0, 1e-7f), 1.f - 1e-7f)) * s_mf[ys0];
            if (py0 >= 0) t0 += __logf(fminf(fmaxf(ppv0, 1e-7f), 1.f - 1e-7f)) * s_mf[py0];
            ce -= t0 * vw0;
            float t1 = __logf(fminf(fmaxf(pyv1, 1e-7f), 1.f - 1e-7f)) * s_mf[ys1];
            if (py1 >= 0) t1 += __logf(fminf(fmaxf(ppv1, 1e-7f), 1.f - 1e-7f)) * s_mf[py1];
            ce -= t1 * vw1;
        }

        // dice intersection terms
        atomicAdd(&s_spt[ys0], pyv0 * vw0);
        if (py0 >= 0) atomicAdd(&s_spt[py0], ppv0 * vw0);
        atomicAdd(&s_spt[ys1], pyv1 * vw1);
        if (py1 >= 0) atomicAdd(&s_spt[py1], ppv1 * vw1);

        // joint histogram
        atomicAdd(&s_hist[pred0 * NC + ys0], vw0);
        atomicAdd(&s_hist[pred1 * NC + ys1], vw1);

        // sink accounting
        const bool pm0 = (s_mf[pred0] == 0.f);
        const bool pm1 = (s_mf[pred1] == 0.f);
        #pragma unroll
        for (int k = 0; k < 4; ++k) {
            const int sk = 4 + 7 * k;
            {
                const bool ysib = (py0 == k) && (ys0 != sk);
                const bool msib = pm0 && (pp0 == k) && (pred0 != sk);
                const bool sib  = ysib || msib;
                if (sib && valid0) sibc[k] += 1.f;
                if ((pp0 == k) && !sib && valid0) {
                    tgtc[k]  += 1.f;
                    sinkI[k] += e[sk].x * rinv0;
                }
            }
            {
                const bool ysib = (py1 == k) && (ys1 != sk);
                const bool msib = pm1 && (pp1 == k) && (pred1 != sk);
                const bool sib  = ysib || msib;
                if (sib && valid1) sibc[k] += 1.f;
                if ((pp1 == k) && !sib && valid1) {
                    tgtc[k]  += 1.f;
                    sinkI[k] += e[sk].y * rinv1;
                }
            }
        }
    }

    // wave reduce -> 4 LDS atomics per value -> private slot stores
    const int lane = tid & 63;
    {
        float r = wave_reduce(ce);
        if (lane == 0) atomicAdd(&s_red[0], r);
    }
    #pragma unroll
    for (int c = 0; c < NC; ++c) {
        float r = wave_reduce(sp[c]);
        if (lane == 0) atomicAdd(&s_red[1 + c], r);
    }
    #pragma unroll
    for (int k = 0; k < 4; ++k) {
        float r = wave_reduce(sinkI[k]);
        if (lane == 0) atomicAdd(&s_red[33 + k], r);
        r = wave_reduce(sibc[k]);
        if (lane == 0) atomicAdd(&s_red[37 + k], r);
        r = wave_reduce(tgtc[k]);
        if (lane == 0) atomicAdd(&s_red[41 + k], r);
    }
    __syncthreads();

    // plain coalesced stores to this block's private slot — zero global atomics
    for (int i = tid; i < NC * NC; i += TPB) wsb[WS_HIST + i] = s_hist[i];
    if (tid == 0) wsb[WS_CE] = s_red[0];
    if (tid < NC) {
        wsb[WS_SP  + tid] = s_red[1 + tid];
        wsb[WS_SPT + tid] = s_spt[tid];
    }
    if (tid < 4) {
        wsb[WS_SINKI + tid] = s_red[33 + tid];
        wsb[WS_SIB   + tid] = s_red[37 + tid];
        wsb[WS_TGT   + tid] = s_red[41 + tid];
    }
}

// sum 384 per-block slots per sample into the final region (coalesced)
__global__ __launch_bounds__(TPB) void reduce_kernel(
    const float* __restrict__ ws, float* __restrict__ wsf)
{
    const int g = blockIdx.x * TPB + threadIdx.x;
    if (g >= 2 * SLOT_STRIDE) return;
    const int b   = g / SLOT_STRIDE;
    const int val = g % SLOT_STRIDE;
    float s = 0.f;
    for (int blk = 0; blk < NB; ++blk)
        s += ws[(size_t)(2 * blk + b) * SLOT_STRIDE + val];
    wsf[(size_t)b * SLOT_STRIDE + val] = s;
}

__global__ __launch_bounds__(64) void finalize_kernel(
    const float* __restrict__ wsf,
    const int*   __restrict__ masks,
    float* __restrict__ out)
{
    const int b = blockIdx.x;
    const float* wsb  = wsf + (size_t)b * SLOT_STRIDE;
    const float* hist = wsb + WS_HIST;
    const int tid = threadIdx.x;

    __shared__ float s_col[NC], s_row[NC], s_dice[NC], s_mf[NC];

    if (tid < NC) {
        float cs = 0.f, rs = 0.f;
        for (int j = 0; j < NC; ++j) {
            cs += hist[j * NC + tid];
            rs += hist[tid * NC + j];
        }
        s_col[tid] = cs;
        s_row[tid] = rs;
        s_mf[tid]  = (masks[b * NC + tid] != 0) ? 1.f : 0.f;
    }
    __syncthreads();

    if (tid < NC) {
        const int c = tid;
        float ycnt, pcnt, tp;
        if (c < 4) {
            int idx[8];
            idx[0] = c;
            for (int j = 0; j < 7; ++j) idx[1 + j] = 4 + 7 * c + j;
            ycnt = s_col[c]; pcnt = s_row[c];
            for (int j = 0; j < 7; ++j) { ycnt += s_col[idx[1 + j]]; pcnt += s_row[idx[1 + j]]; }
            tp = 0.f;
            for (int a = 0; a < 8; ++a)
                for (int d = 0; d < 8; ++d)
                    tp += hist[idx[a] * NC + idx[d]];
        } else {
            ycnt = s_col[c]; pcnt = s_row[c];
            tp = hist[c * NC + c];
        }
        const float mf = s_mf[c];
        out[6 + (b * NC + c) * 3 + 0] = tp * mf;
        out[6 + (b * NC + c) * 3 + 1] = (pcnt - tp) * mf;
        out[6 + (b * NC + c) * 3 + 2] = (ycnt - tp) * mf;
        float dc = 1.f - 2.f * wsb[WS_SPT + c] / (wsb[WS_SP + c] + ycnt + 1e-5f);
        s_dice[c] = dc * mf;
    }
    __syncthreads();

    if (tid == 0) {
        float vw = 0.f, dsum = 0.f, msum = 0.f;
        for (int c = 0; c < NC; ++c) {
            vw   += s_col[c];
            dsum += s_dice[c];
            msum += s_mf[c];
        }
        const float ce   = wsb[WS_CE] / fmaxf(vw, 1.f);
        const float dice = dsum / fmaxf(msum, 1.f);
        float cnt = 0.f, sd = 0.f;
        for (int k = 0; k < 4; ++k) {
            float fl = (wsb[WS_SIB + k] > 0.f) ? 1.f : 0.f;
            float d  = 1.f - (2.f * wsb[WS_SINKI + k] + 1e-5f) /
                             (wsb[WS_SP + 4 + 7 * k] + wsb[WS_TGT + k] + 1e-5f);
            cnt += fl;
            sd  += d * fl;
        }
        const float sink = (cnt > 0.f) ? 0.1f * (sd / fmaxf(cnt, 1.f)) : 0.f;
        out[b * 3 + 0] = ce;
        out[b * 3 + 1] = dice;
        out[b * 3 + 2] = sink;
    }
}

extern "C" void kernel_launch(void* const* d_in, const int* in_sizes, int n_in,
                              void* d_out, int out_size, void* d_ws, size_t ws_size,
                              hipStream_t stream) {
    const float* images  = (const float*)d_in[0];
    const int*   targets = (const int*)d_in[1];
    const int*   masks   = (const int*)d_in[2];
    float* out = (float*)d_out;
    float* ws  = (float*)d_ws;
    float* wsf = ws + FINAL_OFF;

    // out layout: loss (2*3) | cm (2*32*3) | pred (2*96^3) as floats
    voxel_kernel<<<dim3(NSLOT), dim3(TPB), 0, stream>>>(
        images, targets, masks, ws, out + 6 + 2 * NC * 3);
    reduce_kernel<<<dim3((2 * SLOT_STRIDE + TPB - 1) / TPB), dim3(TPB), 0, stream>>>(ws, wsf);
    finalize_kernel<<<dim3(2), dim3(64), 0, stream>>>(wsf, masks, out);
}

// Round 5
// 358.030 us; speedup vs baseline: 1.0408x; 1.0408x over previous
//
#include <hip/hip_runtime.h>

#define NC 32
#define NVOX (96*96*96)
#define NV2  (NVOX/2)     // 442368 float2-voxel pairs per sample
#define NB 768            // blocks per sample (6 blocks/CU total with 2 samples)
#define TPB 256

// per-block workspace slot layout (floats)
#define WS_CE     0
#define WS_SP     32
#define WS_SPT    64
#define WS_SINKI  96
#define WS_SIB    100
#define WS_TGT    104
#define WS_HIST   128
#define SLOT_STRIDE 1152          // 128 + 1024
#define NSLOT     (2 * NB)        // 1536
#define FINAL_OFF (NSLOT * SLOT_STRIDE)
#define NCHUNK    12
#define BLK_PER_CH (NB / NCHUNK)  // 64

__device__ __forceinline__ float wave_reduce(float v) {
    #pragma unroll
    for (int off = 32; off > 0; off >>= 1)
        v += __shfl_down(v, off, 64);
    return v;
}

__global__ __launch_bounds__(TPB, 3) void voxel_kernel(
    const float* __restrict__ images,
    const int*   __restrict__ targets,
    const int*   __restrict__ masks,     // bools promoted to 4-byte on device
    float* __restrict__ ws,
    float* __restrict__ pred_out)
{
    const int slot = blockIdx.x;
    const int b    = slot & 1;          // interleave samples across XCDs
    const int blk  = slot >> 1;
    const int tid  = threadIdx.x;

    __shared__ float s_hist[NC * NC];
    __shared__ float s_spt[NC];
    __shared__ float s_mf[NC];
    __shared__ float s_red[45];         // ce, sp[32], sinkI[4], sib[4], tgt[4]

    for (int i = tid; i < NC * NC; i += TPB) s_hist[i] = 0.f;
    if (tid < 45) s_red[tid] = 0.f;
    if (tid < NC) {
        s_spt[tid] = 0.f;
        s_mf[tid]  = (masks[b * NC + tid] != 0) ? 1.f : 0.f;
    }
    __syncthreads();

    const float2* img2 = (const float2*)(images + (size_t)b * NC * NVOX);
    const int2*   tgt2 = (const int2*)(targets + (size_t)b * NVOX);
    float2*       pout2 = (float2*)(pred_out + (size_t)b * NVOX);
    float*        wsb  = ws + (size_t)slot * SLOT_STRIDE;

    float sp[NC];
    #pragma unroll
    for (int c = 0; c < NC; ++c) sp[c] = 0.f;
    float ce = 0.f;
    float sinkI[4] = {0.f, 0.f, 0.f, 0.f};
    float sibc[4]  = {0.f, 0.f, 0.f, 0.f};
    float tgtc[4]  = {0.f, 0.f, 0.f, 0.f};

    for (int v2 = blk * TPB + tid; v2 < NV2; v2 += NB * TPB) {
        const int2 yy = tgt2[v2];
        const bool valid0 = (yy.x != 255);
        const bool valid1 = (yy.y != 255);
        const int  ys0 = valid0 ? yy.x : 0;
        const int  ys1 = valid1 ? yy.y : 0;
        const float vw0 = valid0 ? 1.f : 0.f;
        const float vw1 = valid1 ? 1.f : 0.f;

        // load 32 channels x 2 voxels; argmax over RAW x (first-max, strict >)
        float2 e[NC];
        float sum0 = 0.f, sum1 = 0.f;
        float best0 = -3.4e38f, best1 = -3.4e38f;
        int   pred0 = 4, pred1 = 4;
        #pragma unroll
        for (int c = 0; c < NC; ++c) {
            const float2 x = img2[(size_t)c * NV2 + v2];
            const float e0 = __expf(x.x);
            const float e1 = __expf(x.y);
            e[c] = make_float2(e0, e1);
            sum0 += e0;
            sum1 += e1;
            if (c >= 4) {
                if (x.x > best0) { best0 = x.x; pred0 = c; }
                if (x.y > best1) { best1 = x.y; pred1 = c; }
            }
        }
        const float rinv0 = 1.f / sum0;
        const float rinv1 = 1.f / sum1;
        pout2[v2] = make_float2((float)pred0, (float)pred1);

        const int pp0 = (pred0 - 4) / 7;
        const int pp1 = (pred1 - 4) / 7;
        const int py0 = (ys0 >= 4) ? (ys0 - 4) / 7 : -1;
        const int py1 = (ys1 >= 4) ? (ys1 - 4) / 7 : -1;

        // per-class prob sums + select p[y], p[parent(y)] for both halves
        float pyv0 = 0.f, ppv0 = 0.f, pyv1 = 0.f, ppv1 = 0.f;
        #pragma unroll
        for (int c = 0; c < NC; ++c) {
            const float p0 = e[c].x * rinv0;
            const float p1 = e[c].y * rinv1;
            sp[c] += p0 * vw0 + p1 * vw1;
            if (c == ys0) pyv0 = p0;
            if (c == py0) ppv0 = p0;
            if (c == ys1) pyv1 = p1;
            if (c == py1) ppv1 = p1;
        }

        // CE
        {
            float t0 = __logf(fminf(fmaxf(pyv0, 1e-7f), 1.f - 1e-7f)) * s_mf[ys0];
            if (py0 >= 0) t0 += __logf(fminf(fmaxf(ppv0, 1e-7f), 1.f - 1e-7f)) * s_mf[py0];
            ce -= t0 * vw0;
            float t1 = __logf(fminf(fmaxf(pyv1, 1e-7f), 1.f - 1e-7f)) * s_mf[ys1];
            if (py1 >= 0) t1 += __logf(fminf(fmaxf(ppv1, 1e-7f), 1.f - 1e-7f)) * s_mf[py1];
            ce -= t1 * vw1;
        }

        // dice intersection terms
        atomicAdd(&s_spt[ys0], pyv0 * vw0);
        if (py0 >= 0) atomicAdd(&s_spt[py0], ppv0 * vw0);
        atomicAdd(&s_spt[ys1], pyv1 * vw1);
        if (py1 >= 0) atomicAdd(&s_spt[py1], ppv1 * vw1);

        // joint histogram
        atomicAdd(&s_hist[pred0 * NC + ys0], vw0);
        atomicAdd(&s_hist[pred1 * NC + ys1], vw1);

        // sink accounting
        const bool pm0 = (s_mf[pred0] == 0.f);
        const bool pm1 = (s_mf[pred1] == 0.f);
        #pragma unroll
        for (int k = 0; k < 4; ++k) {
            const int sk = 4 + 7 * k;
            {
                const bool ysib = (py0 == k) && (ys0 != sk);
                const bool msib = pm0 && (pp0 == k) && (pred0 != sk);
                const bool sib  = ysib || msib;
                if (sib && valid0) sibc[k] += 1.f;
                if ((pp0 == k) && !sib && valid0) {
                    tgtc[k]  += 1.f;
                    sinkI[k] += e[sk].x * rinv0;
                }
            }
            {
                const bool ysib = (py1 == k) && (ys1 != sk);
                const bool msib = pm1 && (pp1 == k) && (pred1 != sk);
                const bool sib  = ysib || msib;
                if (sib && valid1) sibc[k] += 1.f;
                if ((pp1 == k) && !sib && valid1) {
                    tgtc[k]  += 1.f;
                    sinkI[k] += e[sk].y * rinv1;
                }
            }
        }
    }

    // wave reduce -> 4 LDS atomics per value -> private slot stores
    const int lane = tid & 63;
    {
        float r = wave_reduce(ce);
        if (lane == 0) atomicAdd(&s_red[0], r);
    }
    #pragma unroll
    for (int c = 0; c < NC; ++c) {
        float r = wave_reduce(sp[c]);
        if (lane == 0) atomicAdd(&s_red[1 + c], r);
    }
    #pragma unroll
    for (int k = 0; k < 4; ++k) {
        float r = wave_reduce(sinkI[k]);
        if (lane == 0) atomicAdd(&s_red[33 + k], r);
        r = wave_reduce(sibc[k]);
        if (lane == 0) atomicAdd(&s_red[37 + k], r);
        r = wave_reduce(tgtc[k]);
        if (lane == 0) atomicAdd(&s_red[41 + k], r);
    }
    __syncthreads();

    // plain coalesced stores to this block's private slot — zero global atomics
    for (int i = tid; i < NC * NC; i += TPB) wsb[WS_HIST + i] = s_hist[i];
    if (tid == 0) wsb[WS_CE] = s_red[0];
    if (tid < NC) {
        wsb[WS_SP  + tid] = s_red[1 + tid];
        wsb[WS_SPT + tid] = s_spt[tid];
    }
    if (tid < 4) {
        wsb[WS_SINKI + tid] = s_red[33 + tid];
        wsb[WS_SIB   + tid] = s_red[37 + tid];
        wsb[WS_TGT   + tid] = s_red[41 + tid];
    }
}

// stage A: 108 blocks; each sums a 64-slot chunk for 256 values, one atomic each
__global__ __launch_bounds__(TPB) void reduce_kernel(
    const float* __restrict__ ws, float* __restrict__ wsf)
{
    const int v = blockIdx.x * TPB + threadIdx.x;   // value id, 0..2303
    if (v >= 2 * SLOT_STRIDE) return;
    const int b   = v / SLOT_STRIDE;
    const int val = v % SLOT_STRIDE;
    const int blk0 = blockIdx.y * BLK_PER_CH;
    const float* base = ws + (size_t)b * SLOT_STRIDE + val;
    float s = 0.f;
    #pragma unroll 8
    for (int i = 0; i < BLK_PER_CH; ++i)
        s += base[(size_t)(2 * (blk0 + i)) * SLOT_STRIDE];
    atomicAdd(&wsf[v], s);
}

__global__ __launch_bounds__(64) void finalize_kernel(
    const float* __restrict__ wsf,
    const int*   __restrict__ masks,
    float* __restrict__ out)
{
    const int b = blockIdx.x;
    const float* wsb  = wsf + (size_t)b * SLOT_STRIDE;
    const float* hist = wsb + WS_HIST;
    const int tid = threadIdx.x;

    __shared__ float s_col[NC], s_row[NC], s_dice[NC], s_mf[NC];

    if (tid < NC) {
        float cs = 0.f, rs = 0.f;
        for (int j = 0; j < NC; ++j) {
            cs += hist[j * NC + tid];
            rs += hist[tid * NC + j];
        }
        s_col[tid] = cs;
        s_row[tid] = rs;
        s_mf[tid]  = (masks[b * NC + tid] != 0) ? 1.f : 0.f;
    }
    __syncthreads();

    if (tid < NC) {
        const int c = tid;
        float ycnt, pcnt, tp;
        if (c < 4) {
            int idx[8];
            idx[0] = c;
            for (int j = 0; j < 7; ++j) idx[1 + j] = 4 + 7 * c + j;
            ycnt = s_col[c]; pcnt = s_row[c];
            for (int j = 0; j < 7; ++j) { ycnt += s_col[idx[1 + j]]; pcnt += s_row[idx[1 + j]]; }
            tp = 0.f;
            for (int a = 0; a < 8; ++a)
                for (int d = 0; d < 8; ++d)
                    tp += hist[idx[a] * NC + idx[d]];
        } else {
            ycnt = s_col[c]; pcnt = s_row[c];
            tp = hist[c * NC + c];
        }
        const float mf = s_mf[c];
        out[6 + (b * NC + c) * 3 + 0] = tp * mf;
        out[6 + (b * NC + c) * 3 + 1] = (pcnt - tp) * mf;
        out[6 + (b * NC + c) * 3 + 2] = (ycnt - tp) * mf;
        float dc = 1.f - 2.f * wsb[WS_SPT + c] / (wsb[WS_SP + c] + ycnt + 1e-5f);
        s_dice[c] = dc * mf;
    }
    __syncthreads();

    if (tid == 0) {
        float vw = 0.f, dsum = 0.f, msum = 0.f;
        for (int c = 0; c < NC; ++c) {
            vw   += s_col[c];
            dsum += s_dice[c];
            msum += s_mf[c];
        }
        const float ce   = wsb[WS_CE] / fmaxf(vw, 1.f);
        const float dice = dsum / fmaxf(msum, 1.f);
        float cnt = 0.f, sd = 0.f;
        for (int k = 0; k < 4; ++k) {
            float fl = (wsb[WS_SIB + k] > 0.f) ? 1.f : 0.f;
            float d  = 1.f - (2.f * wsb[WS_SINKI + k] + 1e-5f) /
                             (wsb[WS_SP + 4 + 7 * k] + wsb[WS_TGT + k] + 1e-5f);
            cnt += fl;
            sd  += d * fl;
        }
        const float sink = (cnt > 0.f) ? 0.1f * (sd / fmaxf(cnt, 1.f)) : 0.f;
        out[b * 3 + 0] = ce;
        out[b * 3 + 1] = dice;
        out[b * 3 + 2] = sink;
    }
}

extern "C" void kernel_launch(void* const* d_in, const int* in_sizes, int n_in,
                              void* d_out, int out_size, void* d_ws, size_t ws_size,
                              hipStream_t stream) {
    const float* images  = (const float*)d_in[0];
    const int*   targets = (const int*)d_in[1];
    const int*   masks   = (const int*)d_in[2];
    float* out = (float*)d_out;
    float* ws  = (float*)d_ws;
    float* wsf = ws + FINAL_OFF;

    // zero only the tiny final-accumulator region (stage-A atomics target it)
    hipMemsetAsync(wsf, 0, 2 * SLOT_STRIDE * sizeof(float), stream);

    // out layout: loss (2*3) | cm (2*32*3) | pred (2*96^3) as floats
    voxel_kernel<<<dim3(NSLOT), dim3(TPB), 0, stream>>>(
        images, targets, masks, ws, out + 6 + 2 * NC * 3);
    reduce_kernel<<<dim3((2 * SLOT_STRIDE + TPB - 1) / TPB, NCHUNK), dim3(TPB), 0, stream>>>(ws, wsf);
    finalize_kernel<<<dim3(2), dim3(64), 0, stream>>>(wsf, masks, out);
}

// Round 6
// 342.562 us; speedup vs baseline: 1.0878x; 1.0452x over previous
//
#include <hip/hip_runtime.h>

#define NC 32
#define NVOX (96*96*96)
#define NB 512            // blocks per sample; 2*NB = 1024 = exactly 4 blocks/CU
#define TPB 256
#define ROWS 33           // LDS row stride (+1 pad: bank = (tid+c)%32, free 2-way)

// per-block workspace slot layout (floats)
#define WS_CE     0
#define WS_SP     32
#define WS_SPT    64
#define WS_SINKI  96
#define WS_SIB    100
#define WS_TGT    104
#define WS_HIST   128
#define SLOT_STRIDE 1152          // 128 + 1024
#define NSLOT     (2 * NB)        // 1024
#define FINAL_OFF (NSLOT * SLOT_STRIDE)
#define NCHUNK    8
#define BLK_PER_CH (NB / NCHUNK)  // 64

__device__ __forceinline__ float wave_reduce(float v) {
    #pragma unroll
    for (int off = 32; off > 0; off >>= 1)
        v += __shfl_down(v, off, 64);
    return v;
}

__global__ __launch_bounds__(TPB, 4) void voxel_kernel(
    const float* __restrict__ images,
    const int*   __restrict__ targets,
    const int*   __restrict__ masks,     // bools promoted to 4-byte on device
    float* __restrict__ ws,
    float* __restrict__ pred_out)
{
    const int slot = blockIdx.x;
    const int b    = slot & 1;          // interleave samples across XCDs
    const int blk  = slot >> 1;
    const int tid  = threadIdx.x;

    __shared__ float s_e[TPB * ROWS];   // 33.8 KB: per-thread private channel row
    __shared__ float s_hist[NC * NC];
    __shared__ float s_spt[NC];
    __shared__ float s_mf[NC];
    __shared__ float s_red[45];         // ce, sp[32], sinkI[4], sib[4], tgt[4]

    for (int i = tid; i < NC * NC; i += TPB) s_hist[i] = 0.f;
    if (tid < 45) s_red[tid] = 0.f;
    if (tid < NC) {
        s_spt[tid] = 0.f;
        s_mf[tid]  = (masks[b * NC + tid] != 0) ? 1.f : 0.f;
    }
    __syncthreads();

    const float* img  = images + (size_t)b * NC * NVOX;
    const int*   tgt  = targets + (size_t)b * NVOX;
    float*       pout = pred_out + (size_t)b * NVOX;
    float*       wsb  = ws + (size_t)slot * SLOT_STRIDE;
    float*       et   = &s_e[tid * ROWS];   // this thread's private row

    float sp[NC];
    #pragma unroll
    for (int c = 0; c < NC; ++c) sp[c] = 0.f;
    float ce = 0.f;
    float sinkI[4] = {0.f, 0.f, 0.f, 0.f};
    float sibc[4]  = {0.f, 0.f, 0.f, 0.f};
    float tgtc[4]  = {0.f, 0.f, 0.f, 0.f};

    for (int v = blk * TPB + tid; v < NVOX; v += NB * TPB) {
        const int  y     = tgt[v];
        const bool valid = (y != 255);
        const int  ysafe = valid ? y : 0;
        const float vwf  = valid ? 1.f : 0.f;

        // pass 1: stream channels -> exp -> private LDS row; online sum + argmax
        float sum  = 0.f;
        float best = -3.4e38f;
        int   pred = 4;
        #pragma unroll
        for (int c = 0; c < NC; ++c) {
            const float x  = img[(size_t)c * NVOX + v];
            const float ev = __expf(x);
            et[c] = ev;
            sum  += ev;
            if (c >= 4) {                      // static after unroll
                if (x > best) { best = x; pred = c; }
            }
        }
        const float rinv = 1.f / sum;
        pout[v] = (float)pred;

        const int pp = (pred - 4) / 7;                      // parent of pred
        const int py = (ysafe >= 4) ? (ysafe - 4) / 7 : -1; // parent of y or -1
        const int pyi = (py >= 0) ? py : 0;

        // direct-indexed fetches (replaces 4x32 compare/select chains)
        const float pyv  = et[ysafe] * rinv;
        const float ppv  = et[pyi] * rinv;
        const float eskv = et[4 + 7 * pp] * rinv;           // p[sink of pred's parent]

        // CE
        float term = __logf(fminf(fmaxf(pyv, 1e-7f), 1.f - 1e-7f)) * s_mf[ysafe];
        if (py >= 0)
            term += __logf(fminf(fmaxf(ppv, 1e-7f), 1.f - 1e-7f)) * s_mf[pyi];
        ce -= term * vwf;

        // dice intersection terms
        atomicAdd(&s_spt[ysafe], pyv * vwf);
        if (py >= 0) atomicAdd(&s_spt[pyi], ppv * vwf);

        // joint histogram
        atomicAdd(&s_hist[pred * NC + ysafe], vwf);

        // sink accounting (static k indices; only k==pp can take the tgt branch)
        const bool pm = (s_mf[pred] == 0.f);
        #pragma unroll
        for (int k = 0; k < 4; ++k) {
            const int  sk   = 4 + 7 * k;
            const bool ysib = (py == k) && (ysafe != sk);
            const bool msib = pm && (pp == k) && (pred != sk);
            const bool sib  = ysib || msib;
            if (sib && valid) sibc[k] += 1.f;
            if ((pp == k) && !sib && valid) {
                tgtc[k]  += 1.f;
                sinkI[k] += eskv;
            }
        }

        // pass 2: per-class prob sums from LDS row
        const float rw = rinv * vwf;
        #pragma unroll
        for (int c = 0; c < NC; ++c)
            sp[c] = __builtin_fmaf(et[c], rw, sp[c]);
    }

    // wave reduce -> 4 LDS atomics per value -> private slot stores
    const int lane = tid & 63;
    {
        float r = wave_reduce(ce);
        if (lane == 0) atomicAdd(&s_red[0], r);
    }
    #pragma unroll
    for (int c = 0; c < NC; ++c) {
        float r = wave_reduce(sp[c]);
        if (lane == 0) atomicAdd(&s_red[1 + c], r);
    }
    #pragma unroll
    for (int k = 0; k < 4; ++k) {
        float r = wave_reduce(sinkI[k]);
        if (lane == 0) atomicAdd(&s_red[33 + k], r);
        r = wave_reduce(sibc[k]);
        if (lane == 0) atomicAdd(&s_red[37 + k], r);
        r = wave_reduce(tgtc[k]);
        if (lane == 0) atomicAdd(&s_red[41 + k], r);
    }
    __syncthreads();

    // plain coalesced stores to this block's private slot — zero global atomics
    for (int i = tid; i < NC * NC; i += TPB) wsb[WS_HIST + i] = s_hist[i];
    if (tid == 0) wsb[WS_CE] = s_red[0];
    if (tid < NC) {
        wsb[WS_SP  + tid] = s_red[1 + tid];
        wsb[WS_SPT + tid] = s_spt[tid];
    }
    if (tid < 4) {
        wsb[WS_SINKI + tid] = s_red[33 + tid];
        wsb[WS_SIB   + tid] = s_red[37 + tid];
        wsb[WS_TGT   + tid] = s_red[41 + tid];
    }
}

// stage A: each block sums a 64-slot chunk for 256 values, one atomic each
__global__ __launch_bounds__(TPB) void reduce_kernel(
    const float* __restrict__ ws, float* __restrict__ wsf)
{
    const int v = blockIdx.x * TPB + threadIdx.x;   // value id, 0..2303
    if (v >= 2 * SLOT_STRIDE) return;
    const int b   = v / SLOT_STRIDE;
    const int val = v % SLOT_STRIDE;
    const int blk0 = blockIdx.y * BLK_PER_CH;
    const float* base = ws + (size_t)b * SLOT_STRIDE + val;
    float s = 0.f;
    #pragma unroll 8
    for (int i = 0; i < BLK_PER_CH; ++i)
        s += base[(size_t)(2 * (blk0 + i)) * SLOT_STRIDE];
    atomicAdd(&wsf[v], s);
}

__global__ __launch_bounds__(64) void finalize_kernel(
    const float* __restrict__ wsf,
    const int*   __restrict__ masks,
    float* __restrict__ out)
{
    const int b = blockIdx.x;
    const float* wsb  = wsf + (size_t)b * SLOT_STRIDE;
    const float* hist = wsb + WS_HIST;
    const int tid = threadIdx.x;

    __shared__ float s_col[NC], s_row[NC], s_dice[NC], s_mf[NC];

    if (tid < NC) {
        float cs = 0.f, rs = 0.f;
        for (int j = 0; j < NC; ++j) {
            cs += hist[j * NC + tid];
            rs += hist[tid * NC + j];
        }
        s_col[tid] = cs;
        s_row[tid] = rs;
        s_mf[tid]  = (masks[b * NC + tid] != 0) ? 1.f : 0.f;
    }
    __syncthreads();

    if (tid < NC) {
        const int c = tid;
        float ycnt, pcnt, tp;
        if (c < 4) {
            int idx[8];
            idx[0] = c;
            for (int j = 0; j < 7; ++j) idx[1 + j] = 4 + 7 * c + j;
            ycnt = s_col[c]; pcnt = s_row[c];
            for (int j = 0; j < 7; ++j) { ycnt += s_col[idx[1 + j]]; pcnt += s_row[idx[1 + j]]; }
            tp = 0.f;
            for (int a = 0; a < 8; ++a)
                for (int d = 0; d < 8; ++d)
                    tp += hist[idx[a] * NC + idx[d]];
        } else {
            ycnt = s_col[c]; pcnt = s_row[c];
            tp = hist[c * NC + c];
        }
        const float mf = s_mf[c];
        out[6 + (b * NC + c) * 3 + 0] = tp * mf;
        out[6 + (b * NC + c) * 3 + 1] = (pcnt - tp) * mf;
        out[6 + (b * NC + c) * 3 + 2] = (ycnt - tp) * mf;
        float dc = 1.f - 2.f * wsb[WS_SPT + c] / (wsb[WS_SP + c] + ycnt + 1e-5f);
        s_dice[c] = dc * mf;
    }
    __syncthreads();

    if (tid == 0) {
        float vw = 0.f, dsum = 0.f, msum = 0.f;
        for (int c = 0; c < NC; ++c) {
            vw   += s_col[c];
            dsum += s_dice[c];
            msum += s_mf[c];
        }
        const float ce   = wsb[WS_CE] / fmaxf(vw, 1.f);
        const float dice = dsum / fmaxf(msum, 1.f);
        float cnt = 0.f, sd = 0.f;
        for (int k = 0; k < 4; ++k) {
            float fl = (wsb[WS_SIB + k] > 0.f) ? 1.f : 0.f;
            float d  = 1.f - (2.f * wsb[WS_SINKI + k] + 1e-5f) /
                             (wsb[WS_SP + 4 + 7 * k] + wsb[WS_TGT + k] + 1e-5f);
            cnt += fl;
            sd  += d * fl;
        }
        const float sink = (cnt > 0.f) ? 0.1f * (sd / fmaxf(cnt, 1.f)) : 0.f;
        out[b * 3 + 0] = ce;
        out[b * 3 + 1] = dice;
        out[b * 3 + 2] = sink;
    }
}

extern "C" void kernel_launch(void* const* d_in, const int* in_sizes, int n_in,
                              void* d_out, int out_size, void* d_ws, size_t ws_size,
                              hipStream_t stream) {
    const float* images  = (const float*)d_in[0];
    const int*   targets = (const int*)d_in[1];
    const int*   masks   = (const int*)d_in[2];
    float* out = (float*)d_out;
    float* ws  = (float*)d_ws;
    float* wsf = ws + FINAL_OFF;

    // zero only the tiny final-accumulator region (stage-A atomics target it)
    hipMemsetAsync(wsf, 0, 2 * SLOT_STRIDE * sizeof(float), stream);

    // out layout: loss (2*3) | cm (2*32*3) | pred (2*96^3) as floats
    voxel_kernel<<<dim3(NSLOT), dim3(TPB), 0, stream>>>(
        images, targets, masks, ws, out + 6 + 2 * NC * 3);
    reduce_kernel<<<dim3((2 * SLOT_STRIDE + TPB - 1) / TPB, NCHUNK), dim3(TPB), 0, stream>>>(ws, wsf);
    finalize_kernel<<<dim3(2), dim3(64), 0, stream>>>(wsf, masks, out);
}